// Round 4
// baseline (193.073 us; speedup 1.0000x reference)
//
#include <hip/hip_runtime.h>
#include <math.h>

// LSEP loss: log1p( sum_i sum_{j!=y_i} exp(x[i,j] - x[i,y_i]) )
//   = log1p( sum_i exp(-pos_i) * sum_j exp(x[i,j])  -  B )
// C = 340 -> every float4 lies within one row, row = idx4/85.
// n4 = 65536*85 = 5,570,560 = 17 * 256 * 1280: UNROLL=17, 1280 blocks x 256
// threads -> exact cover, 5 blocks/CU exactly.
//
// R1: serialized loop -> latency-bound 64us. R2/R3: batched ILP, neutral
// between UNROLL 8 and 17 -> main is at its memory-system bound; total is
// dominated by the harness's reset fills (356MB ws poison + 89MB d_in
// restore, ~90-110us untouchable). R4: fuse the finalize into main via
// last-block-done (device-scope atomic counter) to drop one kernel launch.

#define NCLS 340
#define NCLS4 85
#define UNROLL 17

__global__ void __launch_bounds__(256) lsep_fused(
        const float* __restrict__ in,
        const int* __restrict__ tgt,
        unsigned int* __restrict__ counter,   // pre-zeroed (8B memset)
        double* __restrict__ partial,         // [gridDim.x]
        float* __restrict__ out,
        int B) {
    const int tid = blockIdx.x * 256 + threadIdx.x;
    const int T = gridDim.x * 256;            // 327,680 threads total
    const float4* __restrict__ in4 = (const float4*)in;

    int   row[UNROLL], t[UNROLL];
    float4 v[UNROLL];
    float pos[UNROLL];

    // epoch 1: all independent loads (17 vector + 17 broadcast tgt)
    #pragma unroll
    for (int u = 0; u < UNROLL; ++u) {
        int idx = tid + u * T;
        row[u] = idx / NCLS4;                 // magic-mul
        v[u]   = in4[idx];
    }
    #pragma unroll
    for (int u = 0; u < UNROLL; ++u)
        t[u] = tgt[row[u]];

    // epoch 2: dependent pos gathers (L1/L2-warm: rows just streamed here)
    #pragma unroll
    for (int u = 0; u < UNROLL; ++u)
        pos[u] = in[row[u] * NCLS + t[u]];

    float s = 0.0f;
    #pragma unroll
    for (int u = 0; u < UNROLL; ++u) {
        float e = __expf(v[u].x) + __expf(v[u].y) +
                  __expf(v[u].z) + __expf(v[u].w);
        s += e * __expf(-pos[u]);
    }

    // wave reduce (64 lanes)
    #pragma unroll
    for (int off = 32; off > 0; off >>= 1)
        s += __shfl_down(s, off, 64);

    __shared__ float wsum[4];
    __shared__ bool amLast;
    int lane = threadIdx.x & 63;
    int wave = threadIdx.x >> 6;
    if (lane == 0) wsum[wave] = s;
    __syncthreads();

    if (threadIdx.x == 0) {
        partial[blockIdx.x] = (double)(wsum[0] + wsum[1] + wsum[2] + wsum[3]);
        __threadfence();                       // release partials (device scope)
        unsigned int old = atomicAdd(counter, 1u);   // device-scope by default
        amLast = (old == (unsigned int)gridDim.x - 1u);
    }
    __syncthreads();

    if (amLast) {
        __threadfence();                       // acquire all partials
        double d = 0.0;
        for (int i = threadIdx.x; i < gridDim.x; i += 256)
            d += partial[i];
        #pragma unroll
        for (int off = 32; off > 0; off >>= 1)
            d += __shfl_down(d, off, 64);
        __shared__ double dsum[4];
        if (lane == 0) dsum[wave] = d;
        __syncthreads();
        if (threadIdx.x == 0) {
            double total = dsum[0] + dsum[1] + dsum[2] + dsum[3];
            out[0] = (float)log1p(total - (double)B);  // remove j==y_i terms
        }
    }
}

extern "C" void kernel_launch(void* const* d_in, const int* in_sizes, int n_in,
                              void* d_out, int out_size, void* d_ws, size_t ws_size,
                              hipStream_t stream) {
    const float* in  = (const float*)d_in[0];
    const int*   tgt = (const int*)d_in[1];
    const int B  = in_sizes[1];          // 65536 rows
    const int n4 = in_sizes[0] / 4;      // 5,570,560 float4s

    const int threads = n4 / UNROLL;     // 327,680 (exact)
    const int blocks  = threads / 256;   // 1280 (exact, 5 blocks/CU)

    unsigned int* counter = (unsigned int*)d_ws;        // 8B (aligned)
    double* partial = (double*)((char*)d_ws + 16);      // 1280 * 8B

    hipMemsetAsync(d_ws, 0, 16, stream);  // zero the arrival counter
    lsep_fused<<<blocks, 256, 0, stream>>>(in, tgt, counter, partial,
                                           (float*)d_out, B);
}

// Round 5
// 132.909 us; speedup vs baseline: 1.4527x; 1.4527x over previous
//
#include <hip/hip_runtime.h>
#include <math.h>

// LSEP loss: log1p( sum_i sum_{j!=y_i} exp(x[i,j] - x[i,y_i]) )
//   = log1p( sum_i exp(-pos_i) * sum_j exp(x[i,j])  -  B )
//
// R1: serialized grid-stride loop -> latency-bound, 64us.
// R2/R3: batched ILP (UNROLL 8 / 17) -> main ~25-28us; total 130us, of
//        which ~98us is the harness's own reset fills (356MB ws poison +
//        89MB d_in restore) -- untouchable.
// R4: fusing finalize via last-block-done dropped VGPRs to 40 (compiler
//     re-serialized the load batch) -> main 95us. REVERTED.
// R5: split the 2-hop gather (tgt[row] -> in[row,tgt]) out of the stream:
//     kernel 1 precomputes scale[row]=exp(-pos) (256KB, L2-resident);
//     main streams float4s with only 1-hop loads so compute can start
//     before the full load batch drains.
//
// C = 340 -> every float4 lies within one row, row = idx4/85.
// n4 = 65536*85 = 5,570,560 = 17 * 256 * 1280: UNROLL=17, 1280 blocks
// (= 5 blocks/CU exactly), zero tail.

#define NCLS 340
#define NCLS4 85
#define UNROLL 17

// kernel 1: scale[i] = exp(-in[i*340 + tgt[i]]), one thread per row
__global__ void __launch_bounds__(256) lsep_scale(
        const float* __restrict__ in,
        const int* __restrict__ tgt,
        float* __restrict__ scale) {
    int i = blockIdx.x * 256 + threadIdx.x;   // 65536 threads exact
    int t = tgt[i];
    scale[i] = __expf(-in[i * NCLS + t]);
}

// kernel 2: partial[b] = sum over block's float4s of exp(v)*scale[row]
__global__ void __launch_bounds__(256) lsep_main(
        const float* __restrict__ in,
        const float* __restrict__ scale,
        double* __restrict__ partial) {
    const int tid = blockIdx.x * 256 + threadIdx.x;
    const int T = gridDim.x * 256;            // 327,680 threads
    const float4* __restrict__ in4 = (const float4*)in;

    float4 v[UNROLL];
    float  sc[UNROLL];

    #pragma unroll
    for (int u = 0; u < UNROLL; ++u) {
        int idx = tid + u * T;
        int row = idx / NCLS4;                // magic-mul
        v[u]  = in4[idx];                     // streaming 16B/lane
        sc[u] = scale[row];                   // broadcast, L2-hit, 1-hop
    }

    float s = 0.0f;
    #pragma unroll
    for (int u = 0; u < UNROLL; ++u) {
        float e = __expf(v[u].x) + __expf(v[u].y) +
                  __expf(v[u].z) + __expf(v[u].w);
        s += e * sc[u];
    }

    // wave reduce (64 lanes)
    #pragma unroll
    for (int off = 32; off > 0; off >>= 1)
        s += __shfl_down(s, off, 64);

    __shared__ float wsum[4];
    int lane = threadIdx.x & 63;
    int wave = threadIdx.x >> 6;
    if (lane == 0) wsum[wave] = s;
    __syncthreads();
    if (threadIdx.x == 0)
        partial[blockIdx.x] = (double)(wsum[0] + wsum[1] + wsum[2] + wsum[3]);
}

// kernel 3: total = sum(partial) ; out = log1p(total - B)
__global__ void __launch_bounds__(256) lsep_reduce(
        const double* __restrict__ partial, int nblocks,
        float* __restrict__ out, int B) {
    double s = 0.0;
    for (int i = threadIdx.x; i < nblocks; i += 256)
        s += partial[i];
    #pragma unroll
    for (int off = 32; off > 0; off >>= 1)
        s += __shfl_down(s, off, 64);
    __shared__ double wsum[4];
    int lane = threadIdx.x & 63;
    int wave = threadIdx.x >> 6;
    if (lane == 0) wsum[wave] = s;
    __syncthreads();
    if (threadIdx.x == 0) {
        double total = wsum[0] + wsum[1] + wsum[2] + wsum[3];
        out[0] = (float)log1p(total - (double)B);   // remove j==y_i terms
    }
}

extern "C" void kernel_launch(void* const* d_in, const int* in_sizes, int n_in,
                              void* d_out, int out_size, void* d_ws, size_t ws_size,
                              hipStream_t stream) {
    const float* in  = (const float*)d_in[0];
    const int*   tgt = (const int*)d_in[1];
    const int B  = in_sizes[1];          // 65536 rows
    const int n4 = in_sizes[0] / 4;      // 5,570,560 float4s

    const int threads = n4 / UNROLL;     // 327,680 (exact)
    const int blocks  = threads / 256;   // 1280 (exact, 5 blocks/CU)

    float*  scale   = (float*)d_ws;                       // 65536 * 4B
    double* partial = (double*)((char*)d_ws + (size_t)B * sizeof(float));

    lsep_scale<<<B / 256, 256, 0, stream>>>(in, tgt, scale);
    lsep_main<<<blocks, 256, 0, stream>>>(in, scale, partial);
    lsep_reduce<<<1, 256, 0, stream>>>(partial, blocks, (float*)d_out, B);
}

// Round 6
// 130.813 us; speedup vs baseline: 1.4759x; 1.0160x over previous
//
#include <hip/hip_runtime.h>
#include <math.h>

// LSEP loss: log1p( sum_i sum_{j!=y_i} exp(x[i,j] - x[i,y_i]) )
//   = log1p( sum_i exp(-pos_i) * sum_j exp(x[i,j])  -  B )
//
// Session summary:
// R1: serialized grid-stride loop -> latency-bound, main 64us.
// R2: batched 8-deep ILP + block partials -> main ~25us, total 130.0us.
// R3: 17-deep ILP -> neutral (131.0). Main is at its memory-system bound.
// R4: last-block-done fusion -> compiler re-serialized loads (VGPR 40),
//     main 95us. REVERTED.
// R5: split pos-gather into a scale kernel -> neutral (132.9); extra
//     dispatch costs ~1.5-3us.
// Fixed harness cost inside the timed window ~98us (356MB d_ws 0xAA
// re-poison at 83% HBM peak + 89MB d_in restore) -- untouchable.
// R6: consolidate to the best-measured 2-kernel structure.
//
// C = 340 -> every float4 lies within one row, row = idx4/85.
// n4 = 65536*85 = 5,570,560 = 17 * 256 * 1280: UNROLL=17, 1280 blocks
// (= 5 blocks/CU exactly), zero tail.

#define NCLS 340
#define NCLS4 85
#define UNROLL 17

__global__ void __launch_bounds__(256) lsep_main(
        const float* __restrict__ in,
        const int* __restrict__ tgt,
        double* __restrict__ partial) {
    const int tid = blockIdx.x * 256 + threadIdx.x;
    const int T = gridDim.x * 256;            // 327,680 threads total
    const float4* __restrict__ in4 = (const float4*)in;

    int   row[UNROLL], t[UNROLL];
    float4 v[UNROLL];
    float pos[UNROLL];

    // epoch 1: all independent loads (17 vector + 17 broadcast tgt)
    #pragma unroll
    for (int u = 0; u < UNROLL; ++u) {
        int idx = tid + u * T;
        row[u] = idx / NCLS4;                 // magic-mul
        v[u]   = in4[idx];
    }
    #pragma unroll
    for (int u = 0; u < UNROLL; ++u)
        t[u] = tgt[row[u]];

    // epoch 2: dependent pos gathers (L1/L2-warm: rows just streamed)
    #pragma unroll
    for (int u = 0; u < UNROLL; ++u)
        pos[u] = in[row[u] * NCLS + t[u]];

    float s = 0.0f;
    #pragma unroll
    for (int u = 0; u < UNROLL; ++u) {
        float e = __expf(v[u].x) + __expf(v[u].y) +
                  __expf(v[u].z) + __expf(v[u].w);
        s += e * __expf(-pos[u]);
    }

    // wave reduce (64 lanes)
    #pragma unroll
    for (int off = 32; off > 0; off >>= 1)
        s += __shfl_down(s, off, 64);

    __shared__ float wsum[4];
    int lane = threadIdx.x & 63;
    int wave = threadIdx.x >> 6;
    if (lane == 0) wsum[wave] = s;
    __syncthreads();
    if (threadIdx.x == 0)
        partial[blockIdx.x] = (double)(wsum[0] + wsum[1] + wsum[2] + wsum[3]);
}

__global__ void __launch_bounds__(256) lsep_reduce(
        const double* __restrict__ partial, int nblocks,
        float* __restrict__ out, int B) {
    double s = 0.0;
    for (int i = threadIdx.x; i < nblocks; i += 256)
        s += partial[i];
    #pragma unroll
    for (int off = 32; off > 0; off >>= 1)
        s += __shfl_down(s, off, 64);
    __shared__ double wsum[4];
    int lane = threadIdx.x & 63;
    int wave = threadIdx.x >> 6;
    if (lane == 0) wsum[wave] = s;
    __syncthreads();
    if (threadIdx.x == 0) {
        double total = wsum[0] + wsum[1] + wsum[2] + wsum[3];
        out[0] = (float)log1p(total - (double)B);   // remove j==y_i terms
    }
}

extern "C" void kernel_launch(void* const* d_in, const int* in_sizes, int n_in,
                              void* d_out, int out_size, void* d_ws, size_t ws_size,
                              hipStream_t stream) {
    const float* in  = (const float*)d_in[0];
    const int*   tgt = (const int*)d_in[1];
    const int B  = in_sizes[1];          // 65536 rows
    const int n4 = in_sizes[0] / 4;      // 5,570,560 float4s

    const int threads = n4 / UNROLL;     // 327,680 (exact)
    const int blocks  = threads / 256;   // 1280 (exact, 5 blocks/CU)

    double* partial = (double*)d_ws;     // 1280 * 8B scratch

    lsep_main<<<blocks, 256, 0, stream>>>(in, tgt, partial);
    lsep_reduce<<<1, 256, 0, stream>>>(partial, blocks, (float*)d_out, B);
}